// Round 2
// baseline (1152.354 us; speedup 1.0000x reference)
//
#include <hip/hip_runtime.h>
#include <stdint.h>

typedef unsigned short u16;
typedef __bf16 bf16x8 __attribute__((ext_vector_type(8)));
typedef float f32x4 __attribute__((ext_vector_type(4)));

__device__ inline u16 f32_to_bf16(float f) {
  union { float f; uint32_t u; } v; v.f = f;
  uint32_t u = v.u;
  u += 0x7FFF + ((u >> 16) & 1);   // round-to-nearest-even
  return (u16)(u >> 16);
}

__device__ inline void async_load16(const void* g, void* l) {
  __builtin_amdgcn_global_load_lds(
      (const __attribute__((address_space(1))) void*)g,
      (__attribute__((address_space(3))) void*)l, 16, 0, 0);
}

#define BM 128
#define BN 128
#define BK 32

// C = A @ B^T (A,B bf16).  A: [M,K] (lda), B: [N,K] (ldb), C: [M,N] (ldc).
// Batch z: offset = (z>>4)*Outer + (z&15)*Inner per matrix (element counts).
// epi: 0 = bf16 store; 1 = scale+causal+relu, bf16 store;
//      2 = +bias, bf16 store; 3 = +bias, FP32 store (C cast to float*).
__global__ __launch_bounds__(256, 2) void gemm_bt(
    const u16* __restrict__ A, const u16* __restrict__ B, void* __restrict__ Cp,
    const float* __restrict__ bias, int K, int lda, int ldb, int ldc,
    int64_t aOuter, int64_t aInner, int64_t bOuter, int64_t bInner,
    int64_t cOuter, int64_t cInner, float scale, int epi)
{
  const int z = blockIdx.z;
  const u16* Ab = A + (int64_t)(z >> 4) * aOuter + (int64_t)(z & 15) * aInner;
  const u16* Bb = B + (int64_t)(z >> 4) * bOuter + (int64_t)(z & 15) * bInner;

  __shared__ u16 As[BM * BK];   // [m][k], k contiguous, 8 KB
  __shared__ u16 Bs[BN * BK];   // [n][k], k contiguous, 8 KB

  const int t = threadIdx.x;
  const int lane = t & 63;
  const int wave = t >> 6;
  const int m0 = blockIdx.y * BM;
  const int n0 = blockIdx.x * BN;
  const int wm = (wave >> 1) * 64;
  const int wn = (wave & 1) * 64;

  // staging: thread t loads 16B chunk (t&3) of rows (t>>2) and (t>>2)+64
  const u16* ga = Ab + (size_t)(m0 + (t >> 2)) * lda + (t & 3) * 8;
  const u16* gb = Bb + (size_t)(n0 + (t >> 2)) * ldb + (t & 3) * 8;
  const size_t a64 = (size_t)64 * lda;
  const size_t b64 = (size_t)64 * ldb;
  u16* lA = As + t * 8;   // byte offset t*16: wave-uniform base + lane*16
  u16* lB = Bs + t * 8;

  f32x4 acc[4][4] = {};

  const int fr = lane & 15;        // m/n within 16-subtile
  const int fq = (lane >> 4) * 8;  // k offset of 8-elem fragment chunk

  for (int kt = 0; kt < K; kt += BK) {
    async_load16(ga, lA);
    async_load16(ga + a64, lA + 2048);
    async_load16(gb, lB);
    async_load16(gb + b64, lB + 2048);
    ga += BK; gb += BK;
    __syncthreads();

    bf16x8 af[4], bfrag[4];
#pragma unroll
    for (int i = 0; i < 4; ++i)
      af[i] = *(const bf16x8*)(As + (wm + i * 16 + fr) * BK + fq);
#pragma unroll
    for (int j = 0; j < 4; ++j)
      bfrag[j] = *(const bf16x8*)(Bs + (wn + j * 16 + fr) * BK + fq);
#pragma unroll
    for (int i = 0; i < 4; ++i)
#pragma unroll
      for (int j = 0; j < 4; ++j)
        acc[i][j] = __builtin_amdgcn_mfma_f32_16x16x32_bf16(af[i], bfrag[j], acc[i][j], 0, 0, 0);
    __syncthreads();
  }

  // C/D layout: row = (lane>>4)*4 + r (M index), col = lane&15 (N index)
  const int er = (lane >> 4) * 4;
  const int ec = lane & 15;
  u16* Cb = (u16*)Cp + (int64_t)(z >> 4) * cOuter + (int64_t)(z & 15) * cInner;
  float* Cf = (float*)Cp + (int64_t)(z >> 4) * cOuter + (int64_t)(z & 15) * cInner;
#pragma unroll
  for (int i = 0; i < 4; ++i) {
#pragma unroll
    for (int j = 0; j < 4; ++j) {
      const int n = n0 + wn + j * 16 + ec;
      const float bv = (epi >= 2) ? bias[n] : 0.f;
#pragma unroll
      for (int r = 0; r < 4; ++r) {
        const int m = m0 + wm + i * 16 + er + r;
        float v = acc[i][j][r];
        if (epi == 1) { v *= scale; v = (n <= m && v > 0.f) ? v : 0.f; }
        else v += bv;
        if (epi == 3) Cf[(size_t)m * ldc + n] = v;
        else          Cb[(size_t)m * ldc + n] = f32_to_bf16(v);
      }
    }
  }
}

// elementwise fp32 -> bf16, n multiple of 2048
__global__ __launch_bounds__(256) void cvt_f32_bf16(
    const float* __restrict__ in, u16* __restrict__ out, int64_t n)
{
  int64_t i = ((int64_t)blockIdx.x * 256 + threadIdx.x) * 8;
  if (i >= n) return;
  float4 a = *(const float4*)(in + i);
  float4 b = *(const float4*)(in + i + 4);
  union { u16 s[8]; uint4 v; } o;
  o.s[0] = f32_to_bf16(a.x); o.s[1] = f32_to_bf16(a.y);
  o.s[2] = f32_to_bf16(a.z); o.s[3] = f32_to_bf16(a.w);
  o.s[4] = f32_to_bf16(b.x); o.s[5] = f32_to_bf16(b.y);
  o.s[6] = f32_to_bf16(b.z); o.s[7] = f32_to_bf16(b.w);
  *(uint4*)(out + i) = o.v;
}

// out[c][r] = bf16(in[r][c]), in fp32. 64x64 tiles. Grid: (cols/64, rows/64, 1).
__global__ __launch_bounds__(256) void transpose_f32_bf16(
    const float* __restrict__ in, u16* __restrict__ out, int ldin, int ldout)
{
  __shared__ u16 tile[64][72];
  const int t = threadIdx.x;
  const int r0 = blockIdx.y * 64;
  const int c0 = blockIdx.x * 64;
  const int lr = t >> 3;
  const int lc = (t & 7) * 8;
#pragma unroll
  for (int p = 0; p < 2; ++p) {
    const int r = lr + p * 32;
    const float4 a = *(const float4*)(in + (size_t)(r0 + r) * ldin + c0 + lc);
    const float4 b = *(const float4*)(in + (size_t)(r0 + r) * ldin + c0 + lc + 4);
    union { u16 s[8]; uint4 v; } o;
    o.s[0] = f32_to_bf16(a.x); o.s[1] = f32_to_bf16(a.y);
    o.s[2] = f32_to_bf16(a.z); o.s[3] = f32_to_bf16(a.w);
    o.s[4] = f32_to_bf16(b.x); o.s[5] = f32_to_bf16(b.y);
    o.s[6] = f32_to_bf16(b.z); o.s[7] = f32_to_bf16(b.w);
    *(uint4*)&tile[r][lc] = o.v;
  }
  __syncthreads();
#pragma unroll
  for (int p = 0; p < 2; ++p) {
    const int c = (t >> 3) + p * 32;
    union { u16 s[8]; uint4 v; } buf;
#pragma unroll
    for (int i = 0; i < 8; ++i) buf.s[i] = tile[lc + i][c];
    *(uint4*)(out + (size_t)(c0 + c) * ldout + r0 + lc) = buf.v;
  }
}

// out[c][r] = in[r][c], bf16 -> bf16, batched. Grid: (cols/64, rows/64, batch).
__global__ __launch_bounds__(256) void transpose_bf16(
    const u16* __restrict__ in, u16* __restrict__ out, int ldin, int ldout,
    int64_t inOuter, int64_t inInner, int64_t outOuter, int64_t outInner)
{
  const int z = blockIdx.z;
  in  += (int64_t)(z >> 4) * inOuter  + (int64_t)(z & 15) * inInner;
  out += (int64_t)(z >> 4) * outOuter + (int64_t)(z & 15) * outInner;
  __shared__ u16 tile[64][72];
  const int t = threadIdx.x;
  const int r0 = blockIdx.y * 64;
  const int c0 = blockIdx.x * 64;
  const int lr = t >> 3;
  const int lc = (t & 7) * 8;
#pragma unroll
  for (int p = 0; p < 2; ++p) {
    const int r = lr + p * 32;
    const uint4 v = *(const uint4*)(in + (size_t)(r0 + r) * ldin + c0 + lc);
    *(uint4*)&tile[r][lc] = v;
  }
  __syncthreads();
#pragma unroll
  for (int p = 0; p < 2; ++p) {
    const int c = (t >> 3) + p * 32;
    union { u16 s[8]; uint4 v; } buf;
#pragma unroll
    for (int i = 0; i < 8; ++i) buf.s[i] = tile[lc + i][c];
    *(uint4*)(out + (size_t)(c0 + c) * ldout + r0 + lc) = buf.v;
  }
}

extern "C" void kernel_launch(void* const* d_in, const int* in_sizes, int n_in,
                              void* d_out, int out_size, void* d_ws, size_t ws_size,
                              hipStream_t stream) {
  const float* x      = (const float*)d_in[0];
  const float* W_attn = (const float*)d_in[1];
  const float* b_attn = (const float*)d_in[2];
  const float* W_proj = (const float*)d_in[3];
  const float* b_proj = (const float*)d_in[4];
  float* out = (float*)d_out;

  const int Bn = 16, T = 256, Cd = 4096, Dd = 256;
  const int BT = Bn * T;          // 4096
  const int C3 = 3 * Cd;          // 12288
  const int64_t headE = (int64_t)T * Dd;          // 65536
  const int64_t qkvE  = (int64_t)BT * C3;         // 50,331,648

  // ws overlay (u16 elems, 235 MB peak):
  //  [0, qkvE)          : qkv [4096,12288]
  //  [qkvE, 2*qkvE)     : Wt_attn [12288,4096]  -> later vt | P | A1
  //  [2*qkvE, +16.8M)   : xb [4096,4096]        -> later y; Wt_proj -> vt slot
  u16* W0 = (u16*)d_ws;
  u16* qkv     = W0;
  u16* Wt_attn = W0 + qkvE;
  u16* vt      = W0 + qkvE;
  u16* P       = W0 + qkvE + 256 * headE;
  u16* A1      = W0 + qkvE + 512 * headE;
  u16* xb      = W0 + 2 * qkvE;
  u16* y       = W0 + 2 * qkvE;
  u16* Wt_proj = W0 + qkvE;       // vt slot, reused after step 6

  dim3 blk(256);

  // 1. xb = bf16(x)
  cvt_f32_bf16<<<dim3((int)((int64_t)BT * Cd / 2048)), blk, 0, stream>>>(
      x, xb, (int64_t)BT * Cd);

  // 2. Wt_attn = bf16(W_attn^T)  ([4096,12288] -> [12288,4096])
  transpose_f32_bf16<<<dim3(C3 / 64, Cd / 64, 1), blk, 0, stream>>>(
      W_attn, Wt_attn, C3, Cd);

  // 3. qkv = xb @ W_attn + b_attn  (bf16 out)
  gemm_bt<<<dim3(C3 / BN, BT / BM, 1), blk, 0, stream>>>(
      xb, Wt_attn, qkv, b_attn, Cd, Cd, Cd, C3,
      0, 0, 0, 0, 0, 0, 1.f, 2);

  // 4. vt[z][d][t] = v[z][t][d]  (v = qkv cols [8192,12288))
  transpose_bf16<<<dim3(4, 4, 256), blk, 0, stream>>>(
      qkv + 2 * Cd, vt, C3, T,
      (int64_t)T * C3, Dd, 16 * headE, headE);

  // 5. P = relu(causal(q @ k^T * D^-0.5)) per head
  gemm_bt<<<dim3(2, 2, 256), blk, 0, stream>>>(
      qkv, qkv + Cd, P, nullptr, Dd, C3, C3, T,
      (int64_t)T * C3, Dd, (int64_t)T * C3, Dd, 16 * headE, headE,
      0.0625f, 1);

  // 6. A1 = P @ v  (vt = v^T is B^T layout)
  gemm_bt<<<dim3(2, 2, 256), blk, 0, stream>>>(
      P, vt, A1, nullptr, T, T, T, Dd,
      16 * headE, headE, 16 * headE, headE, 16 * headE, headE, 1.f, 0);

  // 7. y = A1 @ v, scattered into [BT, C] head layout
  gemm_bt<<<dim3(2, 2, 256), blk, 0, stream>>>(
      A1, vt, y, nullptr, T, T, T, Cd,
      16 * headE, headE, 16 * headE, headE, (int64_t)T * Cd, Dd, 1.f, 0);

  // 8. Wt_proj = bf16(W_proj^T)
  transpose_f32_bf16<<<dim3(Cd / 64, Cd / 64, 1), blk, 0, stream>>>(
      W_proj, Wt_proj, Cd, Cd);

  // 9. out = y @ W_proj + b_proj  (fp32 store)
  gemm_bt<<<dim3(Cd / BN, BT / BM, 1), blk, 0, stream>>>(
      y, Wt_proj, out, b_proj, Cd, Cd, Cd, Cd,
      0, 0, 0, 0, 0, 0, 1.f, 3);
}

// Round 3
// 1064.527 us; speedup vs baseline: 1.0825x; 1.0825x over previous
//
#include <hip/hip_runtime.h>
#include <stdint.h>

typedef unsigned short u16;
typedef __bf16 bf16x8 __attribute__((ext_vector_type(8)));
typedef float f32x4 __attribute__((ext_vector_type(4)));

__device__ inline u16 f32_to_bf16(float f) {
  union { float f; uint32_t u; } v; v.f = f;
  uint32_t u = v.u;
  u += 0x7FFF + ((u >> 16) & 1);   // round-to-nearest-even
  return (u16)(u >> 16);
}

__device__ inline void async_load16(const void* g, void* l) {
  __builtin_amdgcn_global_load_lds(
      (const __attribute__((address_space(1))) void*)g,
      (__attribute__((address_space(3))) void*)l, 16, 0, 0);
}

#define BM 128
#define BN 128
#define BK 64

// C = A @ B^T (A,B bf16).  A: [M,K] (lda), B: [N,K] (ldb), C: [M,N] (ldc).
// Batch z: offset = (z>>4)*Outer + (z&15)*Inner per matrix (element counts).
// epi: 0 = bf16 store; 1 = scale+causal+relu, bf16 store;
//      2 = +bias, bf16 store; 3 = +bias, FP32 store (C cast to float*).
// LDS layout: As[row][chunk] where chunk slot (row,c) holds global k-chunk
// (c ^ (row&7)) — XOR swizzle makes quad ds_read_b128 2-way (free) instead of
// 8-way. global_load_lds forces slot=lane order, so the swizzle is applied to
// the global source address.
__global__ __launch_bounds__(256, 2) void gemm_bt(
    const u16* __restrict__ A, const u16* __restrict__ B, void* __restrict__ Cp,
    const float* __restrict__ bias, int K, int lda, int ldb, int ldc,
    int64_t aOuter, int64_t aInner, int64_t bOuter, int64_t bInner,
    int64_t cOuter, int64_t cInner, float scale, int epi)
{
  const int z = blockIdx.z;
  const u16* Ab = A + (int64_t)(z >> 4) * aOuter + (int64_t)(z & 15) * aInner;
  const u16* Bb = B + (int64_t)(z >> 4) * bOuter + (int64_t)(z & 15) * bInner;

  __shared__ u16 As[BM * BK];   // 16 KB
  __shared__ u16 Bs[BN * BK];   // 16 KB

  const int t = threadIdx.x;
  const int lane = t & 63;
  const int wave = t >> 6;
  const int m0 = blockIdx.y * BM;
  const int n0 = blockIdx.x * BN;
  const int wm = (wave >> 1) * 64;
  const int wn = (wave & 1) * 64;

  // staging: thread t owns LDS slot (row=t>>3, chunk=t&7) of rows r, r+32, r+64, r+96
  const int sr = t >> 3;                 // 0..31
  const int sc = t & 7;                  // chunk slot
  const int csw = sc ^ (sr & 7);         // swizzled global chunk (rows +32 share key)
  const u16* ga = Ab + (size_t)(m0 + sr) * lda + csw * 8;
  const u16* gb = Bb + (size_t)(n0 + sr) * ldb + csw * 8;
  const size_t a32 = (size_t)32 * lda;
  const size_t b32 = (size_t)32 * ldb;
  u16* lA = As + t * 8;   // slot base: wave-uniform + lane*16 (forced layout)
  u16* lB = Bs + t * 8;

  f32x4 acc[4][4] = {};

  const int fr = lane & 15;        // m/n within 16-subtile
  const int q  = lane >> 4;        // k-quad (8 elems each)
  const int xk = fr & 7;           // per-lane swizzle key

  for (int kt = 0; kt < K; kt += BK) {
    async_load16(ga,            lA);
    async_load16(ga +     a32,  lA + 2048);
    async_load16(ga + 2 * a32,  lA + 4096);
    async_load16(ga + 3 * a32,  lA + 6144);
    async_load16(gb,            lB);
    async_load16(gb +     b32,  lB + 2048);
    async_load16(gb + 2 * b32,  lB + 4096);
    async_load16(gb + 3 * b32,  lB + 6144);
    ga += BK; gb += BK;
    __syncthreads();

#pragma unroll
    for (int s = 0; s < 2; ++s) {
      const int ch = (((s << 2) | q) ^ xk) << 3;   // swizzled chunk offset (elems)
      bf16x8 af[4], bfrag[4];
#pragma unroll
      for (int i = 0; i < 4; ++i)
        af[i] = *(const bf16x8*)(As + (wm + i * 16 + fr) * BK + ch);
#pragma unroll
      for (int j = 0; j < 4; ++j)
        bfrag[j] = *(const bf16x8*)(Bs + (wn + j * 16 + fr) * BK + ch);
#pragma unroll
      for (int i = 0; i < 4; ++i)
#pragma unroll
        for (int j = 0; j < 4; ++j)
          acc[i][j] = __builtin_amdgcn_mfma_f32_16x16x32_bf16(af[i], bfrag[j], acc[i][j], 0, 0, 0);
    }
    __syncthreads();
  }

  // C/D layout: row = (lane>>4)*4 + r (M index), col = lane&15 (N index)
  const int er = (lane >> 4) * 4;
  const int ec = lane & 15;
  u16* Cb = (u16*)Cp + (int64_t)(z >> 4) * cOuter + (int64_t)(z & 15) * cInner;
  float* Cf = (float*)Cp + (int64_t)(z >> 4) * cOuter + (int64_t)(z & 15) * cInner;
#pragma unroll
  for (int i = 0; i < 4; ++i) {
#pragma unroll
    for (int j = 0; j < 4; ++j) {
      const int n = n0 + wn + j * 16 + ec;
      const float bv = (epi >= 2) ? bias[n] : 0.f;
#pragma unroll
      for (int r = 0; r < 4; ++r) {
        const int m = m0 + wm + i * 16 + er + r;
        float v = acc[i][j][r];
        if (epi == 1) { v *= scale; v = (n <= m && v > 0.f) ? v : 0.f; }
        else v += bv;
        if (epi == 3) Cf[(size_t)m * ldc + n] = v;
        else          Cb[(size_t)m * ldc + n] = f32_to_bf16(v);
      }
    }
  }
}

// elementwise fp32 -> bf16, n multiple of 2048
__global__ __launch_bounds__(256) void cvt_f32_bf16(
    const float* __restrict__ in, u16* __restrict__ out, int64_t n)
{
  int64_t i = ((int64_t)blockIdx.x * 256 + threadIdx.x) * 8;
  if (i >= n) return;
  float4 a = *(const float4*)(in + i);
  float4 b = *(const float4*)(in + i + 4);
  union { u16 s[8]; uint4 v; } o;
  o.s[0] = f32_to_bf16(a.x); o.s[1] = f32_to_bf16(a.y);
  o.s[2] = f32_to_bf16(a.z); o.s[3] = f32_to_bf16(a.w);
  o.s[4] = f32_to_bf16(b.x); o.s[5] = f32_to_bf16(b.y);
  o.s[6] = f32_to_bf16(b.z); o.s[7] = f32_to_bf16(b.w);
  *(uint4*)(out + i) = o.v;
}

// out[c][r] = bf16(in[r][c]), in fp32. 64x64 tiles. Grid: (cols/64, rows/64, 1).
__global__ __launch_bounds__(256) void transpose_f32_bf16(
    const float* __restrict__ in, u16* __restrict__ out, int ldin, int ldout)
{
  __shared__ u16 tile[64][72];
  const int t = threadIdx.x;
  const int r0 = blockIdx.y * 64;
  const int c0 = blockIdx.x * 64;
  const int lr = t >> 3;
  const int lc = (t & 7) * 8;
#pragma unroll
  for (int p = 0; p < 2; ++p) {
    const int r = lr + p * 32;
    const float4 a = *(const float4*)(in + (size_t)(r0 + r) * ldin + c0 + lc);
    const float4 b = *(const float4*)(in + (size_t)(r0 + r) * ldin + c0 + lc + 4);
    union { u16 s[8]; uint4 v; } o;
    o.s[0] = f32_to_bf16(a.x); o.s[1] = f32_to_bf16(a.y);
    o.s[2] = f32_to_bf16(a.z); o.s[3] = f32_to_bf16(a.w);
    o.s[4] = f32_to_bf16(b.x); o.s[5] = f32_to_bf16(b.y);
    o.s[6] = f32_to_bf16(b.z); o.s[7] = f32_to_bf16(b.w);
    *(uint4*)&tile[r][lc] = o.v;
  }
  __syncthreads();
#pragma unroll
  for (int p = 0; p < 2; ++p) {
    const int c = (t >> 3) + p * 32;
    union { u16 s[8]; uint4 v; } buf;
#pragma unroll
    for (int i = 0; i < 8; ++i) buf.s[i] = tile[lc + i][c];
    *(uint4*)(out + (size_t)(c0 + c) * ldout + r0 + lc) = buf.v;
  }
}

// out[c][r] = in[r][c], bf16 -> bf16, batched. Grid: (cols/64, rows/64, batch).
__global__ __launch_bounds__(256) void transpose_bf16(
    const u16* __restrict__ in, u16* __restrict__ out, int ldin, int ldout,
    int64_t inOuter, int64_t inInner, int64_t outOuter, int64_t outInner)
{
  const int z = blockIdx.z;
  in  += (int64_t)(z >> 4) * inOuter  + (int64_t)(z & 15) * inInner;
  out += (int64_t)(z >> 4) * outOuter + (int64_t)(z & 15) * outInner;
  __shared__ u16 tile[64][72];
  const int t = threadIdx.x;
  const int r0 = blockIdx.y * 64;
  const int c0 = blockIdx.x * 64;
  const int lr = t >> 3;
  const int lc = (t & 7) * 8;
#pragma unroll
  for (int p = 0; p < 2; ++p) {
    const int r = lr + p * 32;
    const uint4 v = *(const uint4*)(in + (size_t)(r0 + r) * ldin + c0 + lc);
    *(uint4*)&tile[r][lc] = v;
  }
  __syncthreads();
#pragma unroll
  for (int p = 0; p < 2; ++p) {
    const int c = (t >> 3) + p * 32;
    union { u16 s[8]; uint4 v; } buf;
#pragma unroll
    for (int i = 0; i < 8; ++i) buf.s[i] = tile[lc + i][c];
    *(uint4*)(out + (size_t)(c0 + c) * ldout + r0 + lc) = buf.v;
  }
}

extern "C" void kernel_launch(void* const* d_in, const int* in_sizes, int n_in,
                              void* d_out, int out_size, void* d_ws, size_t ws_size,
                              hipStream_t stream) {
  const float* x      = (const float*)d_in[0];
  const float* W_attn = (const float*)d_in[1];
  const float* b_attn = (const float*)d_in[2];
  const float* W_proj = (const float*)d_in[3];
  const float* b_proj = (const float*)d_in[4];
  float* out = (float*)d_out;

  const int Bn = 16, T = 256, Cd = 4096, Dd = 256;
  const int BT = Bn * T;          // 4096
  const int C3 = 3 * Cd;          // 12288
  const int64_t headE = (int64_t)T * Dd;          // 65536
  const int64_t qkvE  = (int64_t)BT * C3;         // 50,331,648

  // ws overlay (u16 elems, 235 MB peak):
  //  [0, qkvE)          : qkv [4096,12288]
  //  [qkvE, 2*qkvE)     : Wt_attn [12288,4096]  -> later vt | P | A1
  //  [2*qkvE, +16.8M)   : xb [4096,4096]        -> later y; Wt_proj -> vt slot
  u16* W0 = (u16*)d_ws;
  u16* qkv     = W0;
  u16* Wt_attn = W0 + qkvE;
  u16* vt      = W0 + qkvE;
  u16* P       = W0 + qkvE + 256 * headE;
  u16* A1      = W0 + qkvE + 512 * headE;
  u16* xb      = W0 + 2 * qkvE;
  u16* y       = W0 + 2 * qkvE;
  u16* Wt_proj = W0 + qkvE;       // vt slot, reused after step 6

  dim3 blk(256);

  // 1. xb = bf16(x)
  cvt_f32_bf16<<<dim3((int)((int64_t)BT * Cd / 2048)), blk, 0, stream>>>(
      x, xb, (int64_t)BT * Cd);

  // 2. Wt_attn = bf16(W_attn^T)  ([4096,12288] -> [12288,4096])
  transpose_f32_bf16<<<dim3(C3 / 64, Cd / 64, 1), blk, 0, stream>>>(
      W_attn, Wt_attn, C3, Cd);

  // 3. qkv = xb @ W_attn + b_attn  (bf16 out)
  gemm_bt<<<dim3(C3 / BN, BT / BM, 1), blk, 0, stream>>>(
      xb, Wt_attn, qkv, b_attn, Cd, Cd, Cd, C3,
      0, 0, 0, 0, 0, 0, 1.f, 2);

  // 4. vt[z][d][t] = v[z][t][d]  (v = qkv cols [8192,12288))
  transpose_bf16<<<dim3(4, 4, 256), blk, 0, stream>>>(
      qkv + 2 * Cd, vt, C3, T,
      (int64_t)T * C3, Dd, 16 * headE, headE);

  // 5. P = relu(causal(q @ k^T * D^-0.5)) per head
  gemm_bt<<<dim3(2, 2, 256), blk, 0, stream>>>(
      qkv, qkv + Cd, P, nullptr, Dd, C3, C3, T,
      (int64_t)T * C3, Dd, (int64_t)T * C3, Dd, 16 * headE, headE,
      0.0625f, 1);

  // 6. A1 = P @ v  (vt = v^T is B^T layout)
  gemm_bt<<<dim3(2, 2, 256), blk, 0, stream>>>(
      P, vt, A1, nullptr, T, T, T, Dd,
      16 * headE, headE, 16 * headE, headE, 16 * headE, headE, 1.f, 0);

  // 7. y = A1 @ v, scattered into [BT, C] head layout
  gemm_bt<<<dim3(2, 2, 256), blk, 0, stream>>>(
      A1, vt, y, nullptr, T, T, T, Cd,
      16 * headE, headE, 16 * headE, headE, (int64_t)T * Cd, Dd, 1.f, 0);

  // 8. Wt_proj = bf16(W_proj^T)
  transpose_f32_bf16<<<dim3(Cd / 64, Cd / 64, 1), blk, 0, stream>>>(
      W_proj, Wt_proj, Cd, Cd);

  // 9. out = y @ W_proj + b_proj  (fp32 store)
  gemm_bt<<<dim3(Cd / BN, BT / BM, 1), blk, 0, stream>>>(
      y, Wt_proj, out, b_proj, Cd, Cd, Cd, Cd,
      0, 0, 0, 0, 0, 0, 1.f, 3);
}

// Round 4
// 1032.849 us; speedup vs baseline: 1.1157x; 1.0307x over previous
//
#include <hip/hip_runtime.h>
#include <stdint.h>

typedef unsigned short u16;
typedef __bf16 bf16x8 __attribute__((ext_vector_type(8)));
typedef float f32x4 __attribute__((ext_vector_type(4)));

__device__ inline u16 f32_to_bf16(float f) {
  union { float f; uint32_t u; } v; v.f = f;
  uint32_t u = v.u;
  u += 0x7FFF + ((u >> 16) & 1);   // round-to-nearest-even
  return (u16)(u >> 16);
}

__device__ inline void async_load16(const void* g, void* l) {
  __builtin_amdgcn_global_load_lds(
      (const __attribute__((address_space(1))) void*)g,
      (__attribute__((address_space(3))) void*)l, 16, 0, 0);
}

#define BM 128
#define BN 128
#define BK 64

// C = A @ B^T (A,B bf16).  A: [M,K] (lda), B: [N,K] (ldb), C: [M,N] (ldc).
// epi: 2 = +bias, bf16 store; 3 = +bias, FP32 store.
// LDS XOR chunk swizzle (slot c holds global chunk c^(row&7)) -> 0 bank
// conflicts (verified R3: SQ_LDS_BANK_CONFLICT 5e7 -> 0).
// Grid swizzle: 8-n-tile supergroups cut co-resident L2 footprint ~2x.
__global__ __launch_bounds__(256, 2) void gemm_bt(
    const u16* __restrict__ A, const u16* __restrict__ B, void* __restrict__ Cp,
    const float* __restrict__ bias, int K, int lda, int ldb, int ldc,
    float scale, int epi)
{
  __shared__ u16 As[BM * BK];   // 16 KB
  __shared__ u16 Bs[BN * BK];   // 16 KB

  const int t = threadIdx.x;
  const int lane = t & 63;
  const int wave = t >> 6;

  int bx = blockIdx.x, by = blockIdx.y;
  if ((gridDim.x & 7) == 0) {          // L2 super-tile swizzle
    int bid = by * gridDim.x + bx;
    int tig = gridDim.y << 3;
    int g = bid / tig;
    int l = bid - g * tig;
    bx = (g << 3) + (l & 7);
    by = l >> 3;
  }
  const int m0 = by * BM;
  const int n0 = bx * BN;
  const int wm = (wave >> 1) * 64;
  const int wn = (wave & 1) * 64;

  // staging: thread t owns slot (row=t>>3, chunk=t&7) of rows r, r+32, r+64, r+96
  const int sr = t >> 3;
  const int sc = t & 7;
  const int csw = sc ^ (sr & 7);
  const u16* ga = A + (size_t)(m0 + sr) * lda + csw * 8;
  const u16* gb = B + (size_t)(n0 + sr) * ldb + csw * 8;
  const size_t a32 = (size_t)32 * lda;
  const size_t b32 = (size_t)32 * ldb;
  u16* lA = As + t * 8;
  u16* lB = Bs + t * 8;

  f32x4 acc[4][4] = {};

  const int fr = lane & 15;
  const int q  = lane >> 4;
  const int xk = fr & 7;

  for (int kt = 0; kt < K; kt += BK) {
    async_load16(ga,            lA);
    async_load16(ga +     a32,  lA + 2048);
    async_load16(ga + 2 * a32,  lA + 4096);
    async_load16(ga + 3 * a32,  lA + 6144);
    async_load16(gb,            lB);
    async_load16(gb +     b32,  lB + 2048);
    async_load16(gb + 2 * b32,  lB + 4096);
    async_load16(gb + 3 * b32,  lB + 6144);
    ga += BK; gb += BK;
    __syncthreads();

#pragma unroll
    for (int s = 0; s < 2; ++s) {
      const int ch = (((s << 2) | q) ^ xk) << 3;
      bf16x8 af[4], bfrag[4];
#pragma unroll
      for (int i = 0; i < 4; ++i)
        af[i] = *(const bf16x8*)(As + (wm + i * 16 + fr) * BK + ch);
#pragma unroll
      for (int j = 0; j < 4; ++j)
        bfrag[j] = *(const bf16x8*)(Bs + (wn + j * 16 + fr) * BK + ch);
#pragma unroll
      for (int i = 0; i < 4; ++i)
#pragma unroll
        for (int j = 0; j < 4; ++j)
          acc[i][j] = __builtin_amdgcn_mfma_f32_16x16x32_bf16(af[i], bfrag[j], acc[i][j], 0, 0, 0);
    }
    __syncthreads();
  }

  // C/D layout: row = (lane>>4)*4 + r, col = lane&15
  const int er = (lane >> 4) * 4;
  const int ec = lane & 15;
  u16* Cb = (u16*)Cp;
  float* Cf = (float*)Cp;
#pragma unroll
  for (int i = 0; i < 4; ++i) {
#pragma unroll
    for (int j = 0; j < 4; ++j) {
      const int n = n0 + wn + j * 16 + ec;
      const float bv = bias[n];
#pragma unroll
      for (int r = 0; r < 4; ++r) {
        const int m = m0 + wm + i * 16 + er + r;
        float v = acc[i][j][r] + bv;
        if (epi == 3) Cf[(size_t)m * ldc + n] = v;
        else          Cb[(size_t)m * ldc + n] = f32_to_bf16(v);
      }
    }
  }
}

// Fused attention: per workgroup = (head z, quarter qh: 64 q-rows).
// Phase 1: S = Q@K^T, scale+causal+relu -> Ps (LDS, [64][264] bf16).
// Phase 2: A1 = Ps @ V (vt staged)  -> back into Ps.
// Phase 3: Y  = Ps @ V (vt staged)  -> y global.
__global__ __launch_bounds__(256, 2) void attn_fused(
    const u16* __restrict__ qkv, const u16* __restrict__ vt,
    u16* __restrict__ y)
{
  const int head = blockIdx.x >> 2;    // 0..255
  const int qh   = blockIdx.x & 3;     // q quarter
  const int b    = head >> 4;
  const int h    = head & 15;
  const int C3 = 12288;

  __shared__ u16 Ps[64 * 264];   // P / A1, pad 264 (row 528 B: +4 banks/row, 16B-aligned)
  __shared__ u16 Qs[64 * 64];    // 8 KB
  __shared__ u16 KVs[256 * 64];  // 32 KB (K-tile, then V-tiles)

  const int t = threadIdx.x;
  const int lane = t & 63;
  const int wave = t >> 6;       // wave owns n-cols [wave*64, wave*64+64)
  const int wn = wave * 64;

  const int sr = t >> 3;
  const int sc = t & 7;
  const int csw = sc ^ (sr & 7);

  const u16* qbase = qkv + (size_t)(b * 256 + qh * 64 + sr) * C3 + h * 256 + csw * 8;
  const u16* kbase = qkv + (size_t)(b * 256 + sr) * C3 + 4096 + h * 256 + csw * 8;
  const u16* vbase = vt + (size_t)head * 65536 + (size_t)sr * 256 + csw * 8;

  u16* lQ = Qs + t * 8;
  u16* lK = KVs + t * 8;

  const int fr = lane & 15;
  const int q  = lane >> 4;
  const int xk = fr & 7;
  const int er = q * 4;
  const int ec = fr;

  f32x4 acc[4][4] = {};

  // ---- Phase 1: S = Q @ K^T (K-dim = d = 256) ----
  for (int kt = 0; kt < 256; kt += BK) {
    async_load16(qbase + kt, lQ);
    async_load16(qbase + kt + 32 * C3, lQ + 2048);
#pragma unroll
    for (int p = 0; p < 8; ++p)
      async_load16(kbase + kt + (size_t)p * 32 * C3, lK + p * 2048);
    __syncthreads();
#pragma unroll
    for (int s = 0; s < 2; ++s) {
      const int ch = (((s << 2) | q) ^ xk) << 3;
      bf16x8 af[4], bfrag[4];
#pragma unroll
      for (int i = 0; i < 4; ++i)
        af[i] = *(const bf16x8*)(Qs + (i * 16 + fr) * BK + ch);
#pragma unroll
      for (int j = 0; j < 4; ++j)
        bfrag[j] = *(const bf16x8*)(KVs + (wn + j * 16 + fr) * BK + ch);
#pragma unroll
      for (int i = 0; i < 4; ++i)
#pragma unroll
        for (int j = 0; j < 4; ++j)
          acc[i][j] = __builtin_amdgcn_mfma_f32_16x16x32_bf16(af[i], bfrag[j], acc[i][j], 0, 0, 0);
    }
    __syncthreads();
  }

  // epilogue 1: scale + causal + relu -> Ps[m][t_key]
  {
    const int qg0 = qh * 64;   // global q row of m=0
#pragma unroll
    for (int i = 0; i < 4; ++i)
#pragma unroll
      for (int j = 0; j < 4; ++j) {
        const int tk = wn + j * 16 + ec;   // key index
#pragma unroll
        for (int r = 0; r < 4; ++r) {
          const int m = i * 16 + er + r;
          float v = acc[i][j][r];
          v = (tk <= qg0 + m && v > 0.f) ? v * 0.0625f : 0.f;
          Ps[m * 264 + tk] = f32_to_bf16(v);
        }
      }
  }
  __syncthreads();

  // ---- Phases 2 & 3: acc = Ps @ V (vt as B^T operand) ----
  for (int ph = 0; ph < 2; ++ph) {
#pragma unroll
    for (int i = 0; i < 4; ++i)
#pragma unroll
      for (int j = 0; j < 4; ++j)
        acc[i][j] = (f32x4){0.f, 0.f, 0.f, 0.f};

    for (int kt = 0; kt < 256; kt += BK) {
#pragma unroll
      for (int p = 0; p < 8; ++p)
        async_load16(vbase + kt + (size_t)p * 32 * 256, lK + p * 2048);
      __syncthreads();
#pragma unroll
      for (int s = 0; s < 2; ++s) {
        const int lo = kt + (((s << 2) | q) << 3);       // Ps: padded, no swizzle
        const int ch = (((s << 2) | q) ^ xk) << 3;       // KVs: swizzled
        bf16x8 af[4], bfrag[4];
#pragma unroll
        for (int i = 0; i < 4; ++i)
          af[i] = *(const bf16x8*)(Ps + (i * 16 + fr) * 264 + lo);
#pragma unroll
        for (int j = 0; j < 4; ++j)
          bfrag[j] = *(const bf16x8*)(KVs + (wn + j * 16 + fr) * BK + ch);
#pragma unroll
        for (int i = 0; i < 4; ++i)
#pragma unroll
          for (int j = 0; j < 4; ++j)
            acc[i][j] = __builtin_amdgcn_mfma_f32_16x16x32_bf16(af[i], bfrag[j], acc[i][j], 0, 0, 0);
      }
      __syncthreads();   // also guarantees all Ps reads done before rewrite
    }

    if (ph == 0) {
      // A1 -> Ps
#pragma unroll
      for (int i = 0; i < 4; ++i)
#pragma unroll
        for (int j = 0; j < 4; ++j) {
          const int d = wn + j * 16 + ec;
#pragma unroll
          for (int r = 0; r < 4; ++r)
            Ps[(i * 16 + er + r) * 264 + d] = f32_to_bf16(acc[i][j][r]);
        }
      __syncthreads();
    } else {
      // Y -> y[b*256+qh*64+m][h*256+d]
      u16* yb = y + (size_t)(b * 256 + qh * 64) * 4096 + h * 256;
#pragma unroll
      for (int i = 0; i < 4; ++i)
#pragma unroll
        for (int j = 0; j < 4; ++j) {
          const int d = wn + j * 16 + ec;
#pragma unroll
          for (int r = 0; r < 4; ++r)
            yb[(size_t)(i * 16 + er + r) * 4096 + d] = f32_to_bf16(acc[i][j][r]);
        }
    }
  }
}

// elementwise fp32 -> bf16, n multiple of 2048
__global__ __launch_bounds__(256) void cvt_f32_bf16(
    const float* __restrict__ in, u16* __restrict__ out, int64_t n)
{
  int64_t i = ((int64_t)blockIdx.x * 256 + threadIdx.x) * 8;
  if (i >= n) return;
  float4 a = *(const float4*)(in + i);
  float4 b = *(const float4*)(in + i + 4);
  union { u16 s[8]; uint4 v; } o;
  o.s[0] = f32_to_bf16(a.x); o.s[1] = f32_to_bf16(a.y);
  o.s[2] = f32_to_bf16(a.z); o.s[3] = f32_to_bf16(a.w);
  o.s[4] = f32_to_bf16(b.x); o.s[5] = f32_to_bf16(b.y);
  o.s[6] = f32_to_bf16(b.z); o.s[7] = f32_to_bf16(b.w);
  *(uint4*)(out + i) = o.v;
}

// out[c][r] = bf16(in[r][c]), in fp32. 64x64 tiles. Grid: (cols/64, rows/64, 1).
__global__ __launch_bounds__(256) void transpose_f32_bf16(
    const float* __restrict__ in, u16* __restrict__ out, int ldin, int ldout)
{
  __shared__ u16 tile[64][72];
  const int t = threadIdx.x;
  const int r0 = blockIdx.y * 64;
  const int c0 = blockIdx.x * 64;
  const int lr = t >> 3;
  const int lc = (t & 7) * 8;
#pragma unroll
  for (int p = 0; p < 2; ++p) {
    const int r = lr + p * 32;
    const float4 a = *(const float4*)(in + (size_t)(r0 + r) * ldin + c0 + lc);
    const float4 b = *(const float4*)(in + (size_t)(r0 + r) * ldin + c0 + lc + 4);
    union { u16 s[8]; uint4 v; } o;
    o.s[0] = f32_to_bf16(a.x); o.s[1] = f32_to_bf16(a.y);
    o.s[2] = f32_to_bf16(a.z); o.s[3] = f32_to_bf16(a.w);
    o.s[4] = f32_to_bf16(b.x); o.s[5] = f32_to_bf16(b.y);
    o.s[6] = f32_to_bf16(b.z); o.s[7] = f32_to_bf16(b.w);
    *(uint4*)&tile[r][lc] = o.v;
  }
  __syncthreads();
#pragma unroll
  for (int p = 0; p < 2; ++p) {
    const int c = (t >> 3) + p * 32;
    union { u16 s[8]; uint4 v; } buf;
#pragma unroll
    for (int i = 0; i < 8; ++i) buf.s[i] = tile[lc + i][c];
    *(uint4*)(out + (size_t)(c0 + c) * ldout + r0 + lc) = buf.v;
  }
}

// out[c][r] = in[r][c], bf16 -> bf16, batched. Grid: (cols/64, rows/64, batch).
__global__ __launch_bounds__(256) void transpose_bf16(
    const u16* __restrict__ in, u16* __restrict__ out, int ldin, int ldout,
    int64_t inOuter, int64_t inInner, int64_t outOuter, int64_t outInner)
{
  const int z = blockIdx.z;
  in  += (int64_t)(z >> 4) * inOuter  + (int64_t)(z & 15) * inInner;
  out += (int64_t)(z >> 4) * outOuter + (int64_t)(z & 15) * outInner;
  __shared__ u16 tile[64][72];
  const int t = threadIdx.x;
  const int r0 = blockIdx.y * 64;
  const int c0 = blockIdx.x * 64;
  const int lr = t >> 3;
  const int lc = (t & 7) * 8;
#pragma unroll
  for (int p = 0; p < 2; ++p) {
    const int r = lr + p * 32;
    const uint4 v = *(const uint4*)(in + (size_t)(r0 + r) * ldin + c0 + lc);
    *(uint4*)&tile[r][lc] = v;
  }
  __syncthreads();
#pragma unroll
  for (int p = 0; p < 2; ++p) {
    const int c = (t >> 3) + p * 32;
    union { u16 s[8]; uint4 v; } buf;
#pragma unroll
    for (int i = 0; i < 8; ++i) buf.s[i] = tile[lc + i][c];
    *(uint4*)(out + (size_t)(c0 + c) * ldout + r0 + lc) = buf.v;
  }
}

extern "C" void kernel_launch(void* const* d_in, const int* in_sizes, int n_in,
                              void* d_out, int out_size, void* d_ws, size_t ws_size,
                              hipStream_t stream) {
  const float* x      = (const float*)d_in[0];
  const float* W_attn = (const float*)d_in[1];
  const float* b_attn = (const float*)d_in[2];
  const float* W_proj = (const float*)d_in[3];
  const float* b_proj = (const float*)d_in[4];
  float* out = (float*)d_out;

  const int T = 256, Cd = 4096;
  const int BT = 4096;
  const int C3 = 12288;
  const int64_t headE = (int64_t)T * T;           // 65536
  const int64_t qkvE  = (int64_t)BT * C3;

  // ws overlay (u16 elems):
  //  [0, qkvE)        : qkv [4096,12288]
  //  [qkvE, 2*qkvE)   : Wt_attn -> later vt (32 MB) | Wt_proj
  //  [2*qkvE, ...)    : xb [4096,4096] -> later y
  u16* W0 = (u16*)d_ws;
  u16* qkv     = W0;
  u16* Wt_attn = W0 + qkvE;
  u16* vt      = W0 + qkvE;
  u16* Wt_proj = W0 + qkvE + 256 * headE;   // after vt, both alive during proj
  u16* xb      = W0 + 2 * qkvE;
  u16* y       = W0 + 2 * qkvE;

  dim3 blk(256);

  // 1. xb = bf16(x)
  cvt_f32_bf16<<<dim3((int)((int64_t)BT * Cd / 2048)), blk, 0, stream>>>(
      x, xb, (int64_t)BT * Cd);

  // 2. Wt_attn = bf16(W_attn^T)
  transpose_f32_bf16<<<dim3(C3 / 64, Cd / 64, 1), blk, 0, stream>>>(
      W_attn, Wt_attn, C3, Cd);

  // 3. qkv = xb @ W_attn + b_attn
  gemm_bt<<<dim3(C3 / BN, BT / BM, 1), blk, 0, stream>>>(
      xb, Wt_attn, qkv, b_attn, Cd, Cd, Cd, C3, 1.f, 2);

  // 4. vt[z][d][t] = v[z][t][d]
  transpose_bf16<<<dim3(4, 4, 256), blk, 0, stream>>>(
      qkv + 2 * Cd, vt, C3, T,
      (int64_t)T * C3, (int64_t)T, 16 * headE, headE);

  // 5. fused attention: P = relu(causal(QK^T/16)); A1 = P@V; y = A1@V
  attn_fused<<<dim3(1024), blk, 0, stream>>>(qkv, vt, y);

  // 6. Wt_proj = bf16(W_proj^T)
  transpose_f32_bf16<<<dim3(Cd / 64, Cd / 64, 1), blk, 0, stream>>>(
      W_proj, Wt_proj, Cd, Cd);

  // 7. out = y @ W_proj + b_proj (fp32 store)
  gemm_bt<<<dim3(Cd / BN, BT / BM, 1), blk, 0, stream>>>(
      y, Wt_proj, out, b_proj, Cd, Cd, Cd, Cd, 1.f, 3);
}